// Round 2
// baseline (423.979 us; speedup 1.0000x reference)
//
#include <hip/hip_runtime.h>
#include <stdint.h>

// Deep-TEN encoding, fused one-pass kernel. B=64, N=4096, D=256, K=32.
// Round 2 redesign:
//  - 64-row tiles, each wave OWNS 16 rows end-to-end for stage+phaseA+softmax
//    (softmax over K=32 entirely in-wave -> only 2 barriers per tile).
//  - Single XOR-swizzled bf16 x-buffer (xa) serves phase-A row reads (b128)
//    AND phase-B column gathers (8x u16, conflict-free) -> no transpose buffer.
//  - Perfectly coalesced staging: one wave loads one full 1KB row per instr.
//  - x2 row sums via DPP adds (no LDS traffic).
//  - C fragments for both k-halves VGPR-resident; phase A computes D[k][n]
//    (A = C, B = x), phase B computes E[k][d] (A = w^T from LDS, B = x).
//  - Epilogue: E -= (sum_n w) * C, unsafeAtomicAdd into zeroed d_out.

#define NN 4096
#define DD 256
#define KK 32

typedef __attribute__((ext_vector_type(8))) short short8;   // 8 x bf16
typedef __attribute__((ext_vector_type(4))) float float4v;  // mfma acc

__device__ __forceinline__ unsigned short f2bf(float f) {
    unsigned u = __float_as_uint(f);
    return (unsigned short)((u + 0x7fffu + ((u >> 16) & 1u)) >> 16);  // RNE
}
__device__ __forceinline__ unsigned pk2(float a, float b) {
    return (unsigned)f2bf(a) | ((unsigned)f2bf(b) << 16);
}
__device__ __forceinline__ short8 pack8(float4 a, float4 b) {
    short8 r;
    r[0] = (short)f2bf(a.x); r[1] = (short)f2bf(a.y);
    r[2] = (short)f2bf(a.z); r[3] = (short)f2bf(a.w);
    r[4] = (short)f2bf(b.x); r[5] = (short)f2bf(b.y);
    r[6] = (short)f2bf(b.z); r[7] = (short)f2bf(b.w);
    return r;
}
// chunk swizzle for xa row n: stored chunk index = chunk ^ swx(n)
__device__ __forceinline__ int swx(int n) { return (n & 7) ^ ((n >> 2) & 6); }

// DPP add for wave-64 row-sum (old=0 => safe under either bound_ctrl meaning)
#define DPP_ADD(v, ctrl) \
    ((v) + __int_as_float(__builtin_amdgcn_update_dpp( \
        0, __float_as_int(v), (ctrl), 0xf, 0xf, true)))

__launch_bounds__(256, 2)
__global__ void dten_kernel(const float* __restrict__ X,
                            const float* __restrict__ Cg,
                            const float* __restrict__ Sg,
                            float* __restrict__ out) {
    const int b     = blockIdx.y;
    const int chunk = blockIdx.x;          // 0..15, 256 rows each
    const int tid   = threadIdx.x;
    const int lane  = tid & 63;
    const int wv    = tid >> 6;            // wave 0..3
    const int lk    = lane & 15;
    const int lq    = lane >> 4;           // 0..3

    __shared__ __align__(16) unsigned short xa[64 * 256]; // swizzled bf16 x tile
    __shared__ __align__(16) unsigned short wt[32 * 64];  // swizzled bf16 w^T
    __shared__ __align__(16) float x2s[64];
    __shared__ __align__(16) float c2p[8][32];
    __shared__ __align__(16) float c2s[32];
    __shared__ __align__(16) float wss[4][32];

    // ---- c2[k] = ||C_k||^2, cooperative ----
    {
        int k = tid & 31, seg = tid >> 5;
        const float4* cr = (const float4*)(Cg + k * DD + seg * 32);
        float p = 0.f;
        #pragma unroll
        for (int i = 0; i < 8; ++i) {
            float4 u = cr[i];
            p += u.x*u.x + u.y*u.y + u.z*u.z + u.w*u.w;
        }
        c2p[seg][k] = p;
    }
    __syncthreads();
    if (tid < 32) {
        float s = 0.f;
        #pragma unroll
        for (int seg = 0; seg < 8; ++seg) s += c2p[seg][tid];
        c2s[tid] = s;
    }
    __syncthreads();

    // ---- per-lane k constants: k = 16*kt + 4*lq + r ----
    float sk8[8], c2k8[8];
    #pragma unroll
    for (int kt = 0; kt < 2; ++kt)
        #pragma unroll
        for (int r = 0; r < 4; ++r) {
            int k = 16 * kt + 4 * lq + r;
            sk8[kt * 4 + r]  = Sg[k];
            c2k8[kt * 4 + r] = c2s[k];
        }

    // ---- C fragments (phase-A A-operand): C[16kt+lk][ch*32 + lq*8 + j] ----
    short8 cfrag[2][8];
    #pragma unroll
    for (int kt = 0; kt < 2; ++kt) {
        const float* crow = Cg + (size_t)(16 * kt + lk) * DD + lq * 8;
        #pragma unroll
        for (int ch = 0; ch < 8; ++ch) {
            float4 u0 = *(const float4*)(crow + ch * 32);
            float4 u1 = *(const float4*)(crow + ch * 32 + 4);
            cfrag[kt][ch] = pack8(u0, u1);
        }
    }

    float4v eacc[2][4];
    #pragma unroll
    for (int i = 0; i < 2; ++i)
        #pragma unroll
        for (int j = 0; j < 4; ++j)
            eacc[i][j] = (float4v){0.f, 0.f, 0.f, 0.f};
    float wsr[8] = {0.f, 0.f, 0.f, 0.f, 0.f, 0.f, 0.f, 0.f};

    const int row_base = chunk * 256;
    const int nown = 16 * wv + lk;          // this lane's phase-A column (row n)

    for (int t = 0; t < 4; ++t) {
        const int row0 = row_base + t * 64;
        __syncthreads();   // xa/wt free to overwrite (prev phase B done)

        // ---- stage: wave wv loads rows 16wv..16wv+15, 1 KB coalesced/instr ----
        const float4* xt4 = (const float4*)(X + ((size_t)b * NN + row0) * DD);
        #pragma unroll
        for (int it = 0; it < 16; ++it) {
            int rl = wv * 16 + it;
            float4 v = xt4[rl * 64 + lane];
            // row sum of squares via DPP (lane 63 ends with full 256-elem sum)
            float p = v.x*v.x + v.y*v.y + v.z*v.z + v.w*v.w;
            p = DPP_ADD(p, 0x111); p = DPP_ADD(p, 0x112);
            p = DPP_ADD(p, 0x114); p = DPP_ADD(p, 0x118);
            p = DPP_ADD(p, 0x142); p = DPP_ADD(p, 0x143);
            if (lane == 63) x2s[rl] = p;
            // bf16 pack + swizzled store (chunk = d>>3 = lane>>1, d&7 = 4*(lane&1))
            int cs = (lane >> 1) ^ swx(rl);
            uint2 w2 = make_uint2(pk2(v.x, v.y), pk2(v.z, v.w));
            *(uint2*)&xa[rl * 256 + cs * 8 + 4 * (lane & 1)] = w2;
        }

        // ---- phase A: logits D[k][n] for own 16 rows, all 32 k ----
        float4v a0 = (float4v){0.f, 0.f, 0.f, 0.f};
        float4v a1 = (float4v){0.f, 0.f, 0.f, 0.f};
        {
            const int rowoff = nown * 256;
            const int s = swx(nown);
            #pragma unroll
            for (int ch = 0; ch < 8; ++ch) {
                int c = (4 * ch + lq) ^ s;
                short8 bf = *(const short8*)&xa[rowoff + c * 8];
                a0 = __builtin_amdgcn_mfma_f32_16x16x32_bf16(cfrag[0][ch], bf, a0, 0, 0, 0);
                a1 = __builtin_amdgcn_mfma_f32_16x16x32_bf16(cfrag[1][ch], bf, a1, 0, 0, 0);
            }
        }
        // lane holds logits for n = nown, k = 16*kt + 4*lq + r
        float x2n = x2s[nown];
        float aa[8];
        #pragma unroll
        for (int r = 0; r < 4; ++r) {
            aa[r]     = sk8[r]     * (2.f * a0[r] - x2n - c2k8[r]);
            aa[4 + r] = sk8[4 + r] * (2.f * a1[r] - x2n - c2k8[4 + r]);
        }
        float m = aa[0];
        #pragma unroll
        for (int i = 1; i < 8; ++i) m = fmaxf(m, aa[i]);
        m = fmaxf(m, __shfl_xor(m, 16));
        m = fmaxf(m, __shfl_xor(m, 32));
        float e[8], den = 0.f;
        #pragma unroll
        for (int i = 0; i < 8; ++i) { e[i] = __expf(aa[i] - m); den += e[i]; }
        den += __shfl_xor(den, 16);
        den += __shfl_xor(den, 32);
        float inv = __builtin_amdgcn_rcpf(den);
        {
            const int nhi = nown >> 3, nlo = nown & 7;
            #pragma unroll
            for (int i = 0; i < 8; ++i) {
                float w = e[i] * inv;
                wsr[i] += w;
                int k = 16 * (i >> 2) + 4 * lq + (i & 3);
                wt[k * 64 + ((nhi ^ (k & 7)) << 3) + nlo] = f2bf(w);
            }
        }
        __syncthreads();   // wt + all waves' xa visible

        // ---- phase B: E[k][d] += w^T . x over this tile's 64 rows ----
        #pragma unroll
        for (int nc = 0; nc < 2; ++nc) {
            int nf = nc * 4 + lq;
            short8 af0 = *(const short8*)&wt[lk * 64 + ((nf ^ (lk & 7)) << 3)];
            short8 af1 = *(const short8*)&wt[(16 + lk) * 64 + ((nf ^ (lk & 7)) << 3)];
            #pragma unroll
            for (int dt = 0; dt < 4; ++dt) {
                int cb = 8 * wv + 2 * dt + (lk >> 3);
                short8 bf;
                #pragma unroll
                for (int j = 0; j < 8; ++j) {
                    int n2 = nc * 32 + lq * 8 + j;
                    bf[j] = (short)xa[n2 * 256 + ((cb ^ swx(n2)) << 3) + (lk & 7)];
                }
                eacc[0][dt] = __builtin_amdgcn_mfma_f32_16x16x32_bf16(af0, bf, eacc[0][dt], 0, 0, 0);
                eacc[1][dt] = __builtin_amdgcn_mfma_f32_16x16x32_bf16(af1, bf, eacc[1][dt], 0, 0, 0);
            }
        }
    }

    // ---- wsum: reduce over n ----
    #pragma unroll
    for (int i = 0; i < 8; ++i) {
        wsr[i] += __shfl_xor(wsr[i], 1);
        wsr[i] += __shfl_xor(wsr[i], 2);
        wsr[i] += __shfl_xor(wsr[i], 4);
        wsr[i] += __shfl_xor(wsr[i], 8);
    }
    if (lk == 0) {
        #pragma unroll
        for (int i = 0; i < 8; ++i) {
            int k = 16 * (i >> 2) + 4 * lq + (i & 3);
            wss[wv][k] = wsr[i];
        }
    }
    __syncthreads();

    // ---- epilogue: E -= (sum w) * C, atomic into out ----
    #pragma unroll
    for (int kt = 0; kt < 2; ++kt) {
        #pragma unroll
        for (int r = 0; r < 4; ++r) {
            int k = 16 * kt + 4 * lq + r;
            float wsk = wss[0][k] + wss[1][k] + wss[2][k] + wss[3][k];
            #pragma unroll
            for (int dt = 0; dt < 4; ++dt) {
                int d = 64 * wv + 16 * dt + lk;
                float val = eacc[kt][dt][r] - wsk * Cg[(size_t)k * DD + d];
                unsafeAtomicAdd(&out[((size_t)b * KK + k) * DD + d], val);
            }
        }
    }
}

extern "C" void kernel_launch(void* const* d_in, const int* in_sizes, int n_in,
                              void* d_out, int out_size, void* d_ws, size_t ws_size,
                              hipStream_t stream) {
    const float* X = (const float*)d_in[0];
    const float* C = (const float*)d_in[1];
    const float* S = (const float*)d_in[2];
    float* out = (float*)d_out;
    hipMemsetAsync(out, 0, (size_t)out_size * sizeof(float), stream);
    dim3 grid(16, 64);   // 16 row-chunks x 64 batches
    dten_kernel<<<grid, dim3(256), 0, stream>>>(X, C, S, out);
}

// Round 3
// 386.632 us; speedup vs baseline: 1.0966x; 1.0966x over previous
//
#include <hip/hip_runtime.h>
#include <stdint.h>

// Deep-TEN encoding. B=64, N=4096, D=256, K=32.
// Round 3: atomics -> per-block partial stores to d_ws + reduce kernel.
//  - Main kernel: grid(16 chunks, 64 b), 256 thr, 4 tiles x 64 rows.
//    Stage: coalesced full-row float4 loads (row pairs per lane), perm-pack
//    bf16, write xa (row-major, XOR-swizzled) AND xt (n-pair-packed transpose,
//    XOR-swizzled u32) + DPP row sums. Phase A: in-wave logits+softmax
//    (16 MFMA, C-frags in VGPRs). Phase B: E[k][d] += w^T x from wt/xt
//    (16 MFMA). Epilogue: partial = E - wsum_p*C -> plain stores to ws.
//  - Reduce kernel: out[b][k][d] = sum_c ws[b][c][k][d] (16 partials).
// ws usage: 64*16*32*256*4 = 33.5 MB (< ws_size).

#define NN 4096
#define DD 256
#define KK 32
#define WTP 72   // wt pitch in u16 (16B-aligned rows)

typedef __attribute__((ext_vector_type(8))) short short8;   // 8 x bf16
typedef __attribute__((ext_vector_type(4))) float float4v;  // mfma acc

// truncating bf16 pair pack: low16 = bf16(a), high16 = bf16(b); 1 v_perm_b32
__device__ __forceinline__ unsigned pk2t(float a, float b) {
    return __builtin_amdgcn_perm(__float_as_uint(b), __float_as_uint(a), 0x07060302u);
}
__device__ __forceinline__ unsigned short f2bf_rne(float f) {
    unsigned u = __float_as_uint(f);
    return (unsigned short)((u + 0x7fffu + ((u >> 16) & 1u)) >> 16);
}
__device__ __forceinline__ short8 pack8_rne(float4 a, float4 b) {
    short8 r;
    r[0] = (short)f2bf_rne(a.x); r[1] = (short)f2bf_rne(a.y);
    r[2] = (short)f2bf_rne(a.z); r[3] = (short)f2bf_rne(a.w);
    r[4] = (short)f2bf_rne(b.x); r[5] = (short)f2bf_rne(b.y);
    r[6] = (short)f2bf_rne(b.z); r[7] = (short)f2bf_rne(b.w);
    return r;
}
// xa chunk swizzle (proven conflict-free in R2)
__device__ __forceinline__ int swx(int n) { return (n & 7) ^ ((n >> 2) & 6); }
// xt lane swizzle: g(l), l = d>>2
__device__ __forceinline__ int gfun(int l) { return (l & 15) ^ (l >> 4); }

#define DPP_ADD(v, ctrl) \
    ((v) + __int_as_float(__builtin_amdgcn_update_dpp( \
        0, __float_as_int(v), (ctrl), 0xf, 0xf, true)))

__launch_bounds__(256, 2)
__global__ void dten_kernel(const float* __restrict__ X,
                            const float* __restrict__ Cg,
                            const float* __restrict__ Sg,
                            float* __restrict__ ws) {
    const int b     = blockIdx.y;
    const int chunk = blockIdx.x;          // 0..15, 256 rows each
    const int tid   = threadIdx.x;
    const int lane  = tid & 63;
    const int wv    = tid >> 6;            // wave 0..3
    const int lk    = lane & 15;
    const int lq    = lane >> 4;           // 0..3

    __shared__ __align__(16) unsigned short xa[64 * 256];   // 32 KB row-major
    __shared__ __align__(16) unsigned xt32[256 * 32];       // 32 KB transpose
    __shared__ __align__(16) unsigned short wt[KK * WTP];   // w^T bf16
    __shared__ __align__(16) float x2s[64];
    __shared__ __align__(16) float c2p[8][32];
    __shared__ __align__(16) float c2s[32];
    __shared__ __align__(16) float wss[4][32];

    // ---- c2[k] = ||C_k||^2 ----
    {
        int k = tid & 31, seg = tid >> 5;
        const float4* cr = (const float4*)(Cg + k * DD + seg * 32);
        float p = 0.f;
        #pragma unroll
        for (int i = 0; i < 8; ++i) {
            float4 u = cr[i];
            p += u.x*u.x + u.y*u.y + u.z*u.z + u.w*u.w;
        }
        c2p[seg][k] = p;
    }
    __syncthreads();
    if (tid < 32) {
        float s = 0.f;
        #pragma unroll
        for (int seg = 0; seg < 8; ++seg) s += c2p[seg][tid];
        c2s[tid] = s;
    }
    __syncthreads();

    float sk8[8], c2k8[8];
    #pragma unroll
    for (int kt = 0; kt < 2; ++kt)
        #pragma unroll
        for (int r = 0; r < 4; ++r) {
            int k = 16 * kt + 4 * lq + r;
            sk8[kt * 4 + r]  = Sg[k];
            c2k8[kt * 4 + r] = c2s[k];
        }

    // ---- C fragments (phase-A A-operand), RNE (once) ----
    short8 cfrag[2][8];
    #pragma unroll
    for (int kt = 0; kt < 2; ++kt) {
        const float* crow = Cg + (size_t)(16 * kt + lk) * DD + lq * 8;
        #pragma unroll
        for (int ch = 0; ch < 8; ++ch) {
            float4 u0 = *(const float4*)(crow + ch * 32);
            float4 u1 = *(const float4*)(crow + ch * 32 + 4);
            cfrag[kt][ch] = pack8_rne(u0, u1);
        }
    }

    float4v eacc[2][4];
    #pragma unroll
    for (int i = 0; i < 2; ++i)
        #pragma unroll
        for (int j = 0; j < 4; ++j)
            eacc[i][j] = (float4v){0.f, 0.f, 0.f, 0.f};
    float wsr[8] = {0.f, 0.f, 0.f, 0.f, 0.f, 0.f, 0.f, 0.f};

    const int row_base = chunk * 256;
    const int nown = 16 * wv + lk;
    const int glane = gfun(lane);

    for (int t = 0; t < 4; ++t) {
        const int row0 = row_base + t * 64;
        __syncthreads();   // xa/xt/wt free to overwrite

        // ---- stage: row pairs, fully coalesced (1 KB/instr) ----
        const float4* xt4 = (const float4*)(X + ((size_t)b * NN + row0) * DD);
        #pragma unroll
        for (int it = 0; it < 8; ++it) {
            const int P  = 8 * wv + it;       // pair index within tile, 0..31
            const int r0 = 2 * P, r1 = r0 + 1;
            float4 v0 = xt4[r0 * 64 + lane];
            float4 v1 = xt4[r1 * 64 + lane];
            float p0 = v0.x*v0.x + v0.y*v0.y + v0.z*v0.z + v0.w*v0.w;
            float p1 = v1.x*v1.x + v1.y*v1.y + v1.z*v1.z + v1.w*v1.w;
            p0 = DPP_ADD(p0, 0x111); p1 = DPP_ADD(p1, 0x111);
            p0 = DPP_ADD(p0, 0x112); p1 = DPP_ADD(p1, 0x112);
            p0 = DPP_ADD(p0, 0x114); p1 = DPP_ADD(p1, 0x114);
            p0 = DPP_ADD(p0, 0x118); p1 = DPP_ADD(p1, 0x118);
            p0 = DPP_ADD(p0, 0x142); p1 = DPP_ADD(p1, 0x142);
            p0 = DPP_ADD(p0, 0x143); p1 = DPP_ADD(p1, 0x143);
            if (lane == 63) { x2s[r0] = p0; x2s[r1] = p1; }
            // xa (row-major, swizzled): chunk = lane>>1, off = 4*(lane&1)
            {
                int cs0 = (lane >> 1) ^ swx(r0);
                int cs1 = (lane >> 1) ^ swx(r1);
                *(uint2*)&xa[r0 * 256 + cs0 * 8 + 4 * (lane & 1)] =
                    make_uint2(pk2t(v0.x, v0.y), pk2t(v0.z, v0.w));
                *(uint2*)&xa[r1 * 256 + cs1 * 8 + 4 * (lane & 1)] =
                    make_uint2(pk2t(v1.x, v1.y), pk2t(v1.z, v1.w));
            }
            // xt (transpose, n-pairs packed): word(d) = d*32 + (P ^ g(lane))
            {
                int base = lane * 128 + (P ^ glane);
                xt32[base     ] = pk2t(v0.x, v1.x);
                xt32[base + 32] = pk2t(v0.y, v1.y);
                xt32[base + 64] = pk2t(v0.z, v1.z);
                xt32[base + 96] = pk2t(v0.w, v1.w);
            }
        }

        // ---- phase A: logits for own 16 rows, all 32 k (in-wave) ----
        float4v a0 = (float4v){0.f, 0.f, 0.f, 0.f};
        float4v a1 = (float4v){0.f, 0.f, 0.f, 0.f};
        {
            const int rowoff = nown * 256;
            const int s = swx(nown);
            #pragma unroll
            for (int ch = 0; ch < 8; ++ch) {
                int c = (4 * ch + lq) ^ s;
                short8 bf = *(const short8*)&xa[rowoff + c * 8];
                a0 = __builtin_amdgcn_mfma_f32_16x16x32_bf16(cfrag[0][ch], bf, a0, 0, 0, 0);
                a1 = __builtin_amdgcn_mfma_f32_16x16x32_bf16(cfrag[1][ch], bf, a1, 0, 0, 0);
            }
        }
        float x2n = x2s[nown];
        float aa[8];
        #pragma unroll
        for (int r = 0; r < 4; ++r) {
            aa[r]     = sk8[r]     * (2.f * a0[r] - x2n - c2k8[r]);
            aa[4 + r] = sk8[4 + r] * (2.f * a1[r] - x2n - c2k8[4 + r]);
        }
        float m = aa[0];
        #pragma unroll
        for (int i = 1; i < 8; ++i) m = fmaxf(m, aa[i]);
        m = fmaxf(m, __shfl_xor(m, 16));
        m = fmaxf(m, __shfl_xor(m, 32));
        float e[8], den = 0.f;
        #pragma unroll
        for (int i = 0; i < 8; ++i) { e[i] = __expf(aa[i] - m); den += e[i]; }
        den += __shfl_xor(den, 16);
        den += __shfl_xor(den, 32);
        float inv = __builtin_amdgcn_rcpf(den);
        #pragma unroll
        for (int i = 0; i < 8; ++i) {
            float w = e[i] * inv;
            wsr[i] += w;
            int k = 16 * (i >> 2) + 4 * lq + (i & 3);
            wt[k * WTP + nown] = (unsigned short)(__float_as_uint(w) >> 16);
        }
        __syncthreads();   // wt + all waves' xt visible

        // ---- phase B: E[k][d] += w^T . x over 64 rows ----
        #pragma unroll
        for (int s = 0; s < 2; ++s) {
            short8 af0 = *(const short8*)&wt[lk * WTP + s * 32 + lq * 8];
            short8 af1 = *(const short8*)&wt[(16 + lk) * WTP + s * 32 + lq * 8];
            #pragma unroll
            for (int dt = 0; dt < 4; ++dt) {
                const int d  = 64 * wv + 16 * dt + lk;
                const int gl = gfun(d >> 2);
                const int bb = d * 32 + s * 16;
                short8 bf;
                unsigned* bw = (unsigned*)&bf;
                bw[0] = xt32[bb + ((4 * lq + 0) ^ gl)];
                bw[1] = xt32[bb + ((4 * lq + 1) ^ gl)];
                bw[2] = xt32[bb + ((4 * lq + 2) ^ gl)];
                bw[3] = xt32[bb + ((4 * lq + 3) ^ gl)];
                eacc[0][dt] = __builtin_amdgcn_mfma_f32_16x16x32_bf16(af0, bf, eacc[0][dt], 0, 0, 0);
                eacc[1][dt] = __builtin_amdgcn_mfma_f32_16x16x32_bf16(af1, bf, eacc[1][dt], 0, 0, 0);
            }
        }
    }

    // ---- wsum reduce over n ----
    #pragma unroll
    for (int i = 0; i < 8; ++i) {
        wsr[i] += __shfl_xor(wsr[i], 1);
        wsr[i] += __shfl_xor(wsr[i], 2);
        wsr[i] += __shfl_xor(wsr[i], 4);
        wsr[i] += __shfl_xor(wsr[i], 8);
    }
    if (lk == 0) {
        #pragma unroll
        for (int i = 0; i < 8; ++i) {
            int k = 16 * (i >> 2) + 4 * lq + (i & 3);
            wss[wv][k] = wsr[i];
        }
    }
    __syncthreads();

    // ---- epilogue: partial = E - wsum_p * C, plain stores to ws ----
    float* wsp = ws + (((size_t)b * 16 + chunk) * KK) * DD;
    #pragma unroll
    for (int kt = 0; kt < 2; ++kt) {
        #pragma unroll
        for (int r = 0; r < 4; ++r) {
            int k = 16 * kt + 4 * lq + r;
            float wsk = wss[0][k] + wss[1][k] + wss[2][k] + wss[3][k];
            #pragma unroll
            for (int dt = 0; dt < 4; ++dt) {
                int d = 64 * wv + 16 * dt + lk;
                wsp[k * DD + d] = eacc[kt][dt][r] - wsk * Cg[(size_t)k * DD + d];
            }
        }
    }
}

// out[b][k][d] = sum over 16 chunk-partials
__launch_bounds__(256)
__global__ void reduce_kernel(const float* __restrict__ ws,
                              float* __restrict__ out) {
    const int o = blockIdx.x * 256 + threadIdx.x;   // float4 index, 131072 total
    const int b = o >> 11;                          // 2048 float4 per batch
    const int rest = o & 2047;
    const float4* w4 = (const float4*)ws + ((size_t)b * 16) * 2048 + rest;
    float4 acc = make_float4(0.f, 0.f, 0.f, 0.f);
    #pragma unroll
    for (int c = 0; c < 16; ++c) {
        float4 v = w4[(size_t)c * 2048];
        acc.x += v.x; acc.y += v.y; acc.z += v.z; acc.w += v.w;
    }
    ((float4*)out)[o] = acc;
}

extern "C" void kernel_launch(void* const* d_in, const int* in_sizes, int n_in,
                              void* d_out, int out_size, void* d_ws, size_t ws_size,
                              hipStream_t stream) {
    const float* X = (const float*)d_in[0];
    const float* C = (const float*)d_in[1];
    const float* S = (const float*)d_in[2];
    float* out = (float*)d_out;
    float* ws  = (float*)d_ws;   // 33.5 MB partials
    dim3 grid(16, 64);
    dten_kernel<<<grid, dim3(256), 0, stream>>>(X, C, S, ws);
    reduce_kernel<<<dim3(512), dim3(256), 0, stream>>>(ws, out);
}